// Round 2
// baseline (314.354 us; speedup 1.0000x reference)
//
#include <hip/hip_runtime.h>
#include <hip/hip_fp16.h>
#include <math.h>

#define T_DIM 2048
#define B_DIM 2
#define C_DIM 1024
#define H_DIM 16
#define M_DIM 4096   // B*T

typedef _Float16 f16x8 __attribute__((ext_vector_type(8)));
typedef _Float16 f16x4 __attribute__((ext_vector_type(4)));
typedef float    f32x4 __attribute__((ext_vector_type(4)));

// async global->LDS, 16 bytes per lane (wave-uniform base + lane*16 dest)
#define ASYNC_COPY16(gsrc, ldst) \
  __builtin_amdgcn_global_load_lds( \
    (__attribute__((address_space(1))) unsigned int*)(gsrc), \
    (__attribute__((address_space(3))) unsigned int*)(ldst), 16, 0, 0)

// ---------------- convert x (fp32) -> f16 ----------------
__global__ __launch_bounds__(256) void conv_x_kernel(const float* __restrict__ x,
                                                     _Float16* __restrict__ xh, int n4)
{
    int i = blockIdx.x * 256 + threadIdx.x;
    if (i >= n4) return;
    float4 v = ((const float4*)x)[i];
    f16x4 o;
    o[0] = (_Float16)v.x; o[1] = (_Float16)v.y;
    o[2] = (_Float16)v.z; o[3] = (_Float16)v.w;
    ((f16x4*)xh)[i] = o;
}

// ---------------- transpose + convert W (K x N fp32) -> WT (N x K f16) ----------------
__global__ __launch_bounds__(256) void transpose_f16_kernel(const float* __restrict__ W,
                                                            _Float16* __restrict__ WT,
                                                            int K, int N)
{
    __shared__ float tile[32][33];
    const int nbk = K >> 5;
    const int bk = blockIdx.x % nbk;
    const int bn = blockIdx.x / nbk;
    const int tx = threadIdx.x & 31, ty = threadIdx.x >> 5;
#pragma unroll
    for (int r = ty; r < 32; r += 8)
        tile[r][tx] = W[(long)(bk * 32 + r) * N + bn * 32 + tx];
    __syncthreads();
#pragma unroll
    for (int r = ty; r < 32; r += 8)
        WT[(long)(bn * 32 + r) * K + bk * 32 + tx] = (_Float16)tile[tx][r];
}

// ---------------- f16 MFMA GEMM: C[M,N] = A[M,K] * Bt[N,K]^T ----------------
// 128x128 tile, BK=32, 4 waves (2x2), each wave 64x64 via 4x4 16x16 fragments.
template<int EPI>
__global__ __launch_bounds__(256) void gemm_f16_kernel(
    const _Float16* __restrict__ A, const _Float16* __restrict__ Bt,
    float* __restrict__ C, int M, int N, int K,
    const float* __restrict__ ln_scale, const float* __restrict__ ln_delta,
    const float* __restrict__ ln_bias)
{
    __shared__ __attribute__((aligned(16))) _Float16 As[128 * 32];
    __shared__ __attribute__((aligned(16))) _Float16 Bs[128 * 32];

    const int tid  = threadIdx.x;
    const int lane = tid & 63;
    const int wave = tid >> 6;
    const int wr = wave >> 1, wc = wave & 1;
    const int ntn = N >> 7;
    const int m0 = (blockIdx.x / ntn) << 7;
    const int n0 = (blockIdx.x % ntn) << 7;

    f32x4 acc[4][4] = {};

    // staging geometry: chunk (i*4+wave)*1024B + lane*16B; row = byte/64, col = (byte%64)/2
    const int off0 = (wave << 10) + (lane << 4);   // bytes, i = 0
    const int e0 = off0 >> 1;                      // f16 elems
    const int e1 = e0 + 2048;                      // i = 1 (+4096 B)
    const int r0 = e0 >> 5, c0 = e0 & 31;
    const int r1 = r0 + 64, c1 = c0;

    const _Float16* a0 = A  + (long)(m0 + r0) * K + c0;
    const _Float16* a1 = A  + (long)(m0 + r1) * K + c1;
    const _Float16* b0 = Bt + (long)(n0 + r0) * K + c0;
    const _Float16* b1 = Bt + (long)(n0 + r1) * K + c1;

    const int fr = lane & 15;
    const int kb = (lane >> 4) << 3;  // k offset within BK=32: 0/8/16/24

    for (int k0 = 0; k0 < K; k0 += 32) {
        __syncthreads();  // prior reads done before overwrite
        ASYNC_COPY16(a0 + k0, As + e0);
        ASYNC_COPY16(a1 + k0, As + e1);
        ASYNC_COPY16(b0 + k0, Bs + e0);
        ASYNC_COPY16(b1 + k0, Bs + e1);
        __syncthreads();  // drains vmcnt before barrier -> LDS ready

        f16x8 af[4], bf[4];
#pragma unroll
        for (int i = 0; i < 4; i++)
            af[i] = *(const f16x8*)&As[(((wr << 6) + (i << 4) + fr) << 5) + kb];
#pragma unroll
        for (int j = 0; j < 4; j++)
            bf[j] = *(const f16x8*)&Bs[(((wc << 6) + (j << 4) + fr) << 5) + kb];
#pragma unroll
        for (int i = 0; i < 4; i++)
#pragma unroll
            for (int j = 0; j < 4; j++)
                acc[i][j] = __builtin_amdgcn_mfma_f32_16x16x32_f16(af[i], bf[j], acc[i][j], 0, 0, 0);
    }

    // epilogue: C/D mapping col = lane&15, row = (lane>>4)*4 + r
    const int rsub = (lane >> 4) << 2;
    const float lsc = EPI ? ln_scale[0] : 0.f;
#pragma unroll
    for (int j = 0; j < 4; j++) {
        const int col = n0 + (wc << 6) + (j << 4) + fr;
        float ld = 0.f, lb = 0.f;
        if (EPI) { ld = ln_delta[col]; lb = ln_bias[col]; }
#pragma unroll
        for (int i = 0; i < 4; i++) {
            const int rbase = m0 + (wr << 6) + (i << 4) + rsub;
#pragma unroll
            for (int r = 0; r < 4; r++) {
                float v = acc[i][j][r];
                if (EPI) v = ld * tanhf(lsc * v) + lb;
                C[(long)(rbase + r) * N + col] = v;
            }
        }
    }
}

// ---------------- spiral: two steps in-place on (q,k) of qkv ----------------
__device__ inline void spiral2(float& xi, float& xj, float xl)
{
    const float CS = 0.9950041652780258f;   // cos(0.1)
    const float SN = 0.09983341664682815f;  // sin(0.1)
#pragma unroll
    for (int s = 0; s < 2; s++) {
        float r = sqrtf(xi * xi + xj * xj + xl * xl);
        r = fmaxf(r, 1e-8f);
        const float coef = (6.0f - r) / r;   // radial = coef * x
        const float yi = CS * xi - SN * xj;
        const float yj = SN * xi + CS * xj;
        const float nxi = xi + 0.1f * (yi - xi + coef * xi);
        const float nxj = xj + 0.1f * (yj - xj + coef * xj);
        const float nxl = xl + 0.1f * (coef * xl);  // (y-x) l-comp is 0
        xi = nxi; xj = nxj; xl = nxl;
    }
}

__global__ __launch_bounds__(256) void spiral_kernel(float* __restrict__ qkv)
{
    const int i = blockIdx.x * 256 + threadIdx.x;   // over M*256 float4-groups
    const int row = i >> 8;
    const int c4 = (i & 255) << 2;
    const long base = (long)row * 3072 + c4;
    float4 q = *(const float4*)&qkv[base];
    float4 k = *(const float4*)&qkv[base + 1024];
    float4 v = *(const float4*)&qkv[base + 2048];
    spiral2(q.x, k.x, v.x);
    spiral2(q.y, k.y, v.y);
    spiral2(q.z, k.z, v.z);
    spiral2(q.w, k.w, v.w);
    *(float4*)&qkv[base]        = q;
    *(float4*)&qkv[base + 1024] = k;
}

// ---------------- local causal windowed attention with sink ----------------
// one wave per (b,h,t); lane = head dim
__global__ __launch_bounds__(256) void attn_kernel(const float* __restrict__ qkv,
                                                   const float* __restrict__ sinks,
                                                   _Float16* __restrict__ yh)
{
    const int lane = threadIdx.x & 63;
    int flat = (blockIdx.x << 2) + (threadIdx.x >> 6);  // (b*H + h)*T + t
    const int t  = flat & (T_DIM - 1);
    const int bh = flat >> 11;
    const int h  = bh & (H_DIM - 1);
    const int b  = bh >> 4;

    const long rowbase = (long)(b * T_DIM + t) * 3072;
    const int hc = (h << 6) + lane;
    const float qf = qkv[rowbase + hc] * 0.125f;  // 1/sqrt(64)

    const int jlo = (t >= 16) ? 0 : (16 - t);
    float sc[17];
#pragma unroll
    for (int j = 0; j < 17; j++) {
        float s = -__builtin_inff();
        if (j >= jlo) {
            const long rk = rowbase + (long)(j - 16) * 3072;
            s = qf * qkv[rk + 1024 + hc];
#pragma unroll
            for (int d = 1; d < 64; d <<= 1) s += __shfl_xor(s, d);
        }
        sc[j] = s;
    }

    const float sink = sinks[h];
    float m = sink;
#pragma unroll
    for (int j = 0; j < 17; j++) m = fmaxf(m, sc[j]);
    float denom = expf(sink - m);
    float att[17];
#pragma unroll
    for (int j = 0; j < 17; j++) { float e = expf(sc[j] - m); att[j] = e; denom += e; }

    float acc = 0.f;
#pragma unroll
    for (int j = 0; j < 17; j++) {
        if (j >= jlo) {
            const long rv = rowbase + (long)(j - 16) * 3072;
            acc += att[j] * qkv[rv + 2048 + hc];
        }
    }
    yh[(long)(b * T_DIM + t) * 1024 + hc] = (_Float16)(acc / denom);
}

extern "C" void kernel_launch(void* const* d_in, const int* in_sizes, int n_in,
                              void* d_out, int out_size, void* d_ws, size_t ws_size,
                              hipStream_t stream)
{
    const float* x        = (const float*)d_in[0];
    const float* W_attn   = (const float*)d_in[1];
    const float* W_proj   = (const float*)d_in[2];
    const float* sinks    = (const float*)d_in[3];
    const float* ln_scale = (const float*)d_in[4];
    const float* ln_delta = (const float*)d_in[5];
    const float* ln_bias  = (const float*)d_in[6];
    float* out = (float*)d_out;

    char* ws = (char*)d_ws;
    _Float16* xh  = (_Float16*)(ws);                          //  8 MiB: 4096x1024 f16
    _Float16* WaT = (_Float16*)(ws + (size_t)( 8u << 20));    //  6 MiB: 3072x1024 f16
    _Float16* WpT = (_Float16*)(ws + (size_t)(14u << 20));    //  2 MiB: 1024x1024 f16
    float*    qkv = (float*)   (ws + (size_t)(16u << 20));    // 48 MiB: 4096x3072 f32
    _Float16* yh  = (_Float16*)(ws + (size_t)(64u << 20));    //  8 MiB: 4096x1024 f16

    // 1. x -> f16
    conv_x_kernel<<<4096, 256, 0, stream>>>(x, xh, 1048576);
    // 2. W_attn (1024x3072) -> WaT (3072x1024) f16
    transpose_f16_kernel<<<(1024 / 32) * (3072 / 32), 256, 0, stream>>>(W_attn, WaT, 1024, 3072);
    // 3. W_proj (1024x1024) -> WpT (1024x1024) f16
    transpose_f16_kernel<<<(1024 / 32) * (1024 / 32), 256, 0, stream>>>(W_proj, WpT, 1024, 1024);
    // 4. qkv = x @ W_attn   (M=4096, N=3072, K=1024)
    gemm_f16_kernel<0><<<32 * 24, 256, 0, stream>>>(xh, WaT, qkv, 4096, 3072, 1024,
                                                    nullptr, nullptr, nullptr);
    // 5. spiral^2 on (q,k)
    spiral_kernel<<<4096, 256, 0, stream>>>(qkv);
    // 6. local attention -> yh (f16, (b,t,h*64+d) layout)
    attn_kernel<<<16384, 256, 0, stream>>>(qkv, sinks, yh);
    // 7. out = ln_delta * tanh(ln_scale * (yh @ W_proj)) + ln_bias
    gemm_f16_kernel<1><<<32 * 8, 256, 0, stream>>>(yh, WpT, out, 4096, 1024, 1024,
                                                   ln_scale, ln_delta, ln_bias);
}

// Round 3
// 198.330 us; speedup vs baseline: 1.5850x; 1.5850x over previous
//
#include <hip/hip_runtime.h>
#include <hip/hip_fp16.h>
#include <math.h>

#define T_DIM 2048
#define B_DIM 2
#define C_DIM 1024
#define H_DIM 16
#define M_DIM 4096   // B*T

typedef _Float16 f16x8 __attribute__((ext_vector_type(8)));
typedef _Float16 f16x4 __attribute__((ext_vector_type(4)));
typedef _Float16 f16x2 __attribute__((ext_vector_type(2)));
typedef float    f32x4 __attribute__((ext_vector_type(4)));

#if defined(__has_builtin)
#  if __has_builtin(__builtin_amdgcn_fdot2)
#    define HAVE_FDOT2 1
#  endif
#endif

static __device__ __forceinline__ float FDOT2(f16x2 a, f16x2 b, float c)
{
#ifdef HAVE_FDOT2
    return __builtin_amdgcn_fdot2(a, b, c, false);
#else
    return c + (float)a[0] * (float)b[0] + (float)a[1] * (float)b[1];
#endif
}

// async global->LDS, 16 bytes per lane (wave-uniform base + lane*16 dest)
#define ASYNC_COPY16(gsrc, ldst) \
  __builtin_amdgcn_global_load_lds( \
    (__attribute__((address_space(1))) unsigned int*)(gsrc), \
    (__attribute__((address_space(3))) unsigned int*)(ldst), 16, 0, 0)

// ---------------- convert x (fp32) -> f16 ----------------
__global__ __launch_bounds__(256) void conv_x_kernel(const float* __restrict__ x,
                                                     _Float16* __restrict__ xh, int n4)
{
    int i = blockIdx.x * 256 + threadIdx.x;
    if (i >= n4) return;
    float4 v = ((const float4*)x)[i];
    f16x4 o;
    o[0] = (_Float16)v.x; o[1] = (_Float16)v.y;
    o[2] = (_Float16)v.z; o[3] = (_Float16)v.w;
    ((f16x4*)xh)[i] = o;
}

// ---------------- transpose + convert W (K x N fp32) -> WT (N x K f16) ----------------
__global__ __launch_bounds__(256) void transpose_f16_kernel(const float* __restrict__ W,
                                                            _Float16* __restrict__ WT,
                                                            int K, int N)
{
    __shared__ float tile[32][33];
    const int nbk = K >> 5;
    const int bk = blockIdx.x % nbk;
    const int bn = blockIdx.x / nbk;
    const int tx = threadIdx.x & 31, ty = threadIdx.x >> 5;
#pragma unroll
    for (int r = ty; r < 32; r += 8)
        tile[r][tx] = W[(long)(bk * 32 + r) * N + bn * 32 + tx];
    __syncthreads();
#pragma unroll
    for (int r = ty; r < 32; r += 8)
        WT[(long)(bn * 32 + r) * K + bk * 32 + tx] = (_Float16)tile[tx][r];
}

// ---------------- f16 MFMA GEMM: C[M,N] = A[M,K] * Bt[N,K]^T ----------------
// 128x128 tile, BK=32, 4 waves (2x2), each wave 64x64 via 4x4 16x16 fragments.
template<int EPI>
__global__ __launch_bounds__(256) void gemm_f16_kernel(
    const _Float16* __restrict__ A, const _Float16* __restrict__ Bt,
    float* __restrict__ C, int M, int N, int K,
    const float* __restrict__ ln_scale, const float* __restrict__ ln_delta,
    const float* __restrict__ ln_bias)
{
    __shared__ __attribute__((aligned(16))) _Float16 As[128 * 32];
    __shared__ __attribute__((aligned(16))) _Float16 Bs[128 * 32];

    const int tid  = threadIdx.x;
    const int lane = tid & 63;
    const int wave = tid >> 6;
    const int wr = wave >> 1, wc = wave & 1;
    const int ntn = N >> 7;
    const int m0 = (blockIdx.x / ntn) << 7;
    const int n0 = (blockIdx.x % ntn) << 7;

    f32x4 acc[4][4] = {};

    const int off0 = (wave << 10) + (lane << 4);   // bytes, i = 0
    const int e0 = off0 >> 1;                      // f16 elems
    const int e1 = e0 + 2048;                      // i = 1 (+4096 B)
    const int r0 = e0 >> 5, c0 = e0 & 31;
    const int r1 = r0 + 64, c1 = c0;

    const _Float16* a0 = A  + (long)(m0 + r0) * K + c0;
    const _Float16* a1 = A  + (long)(m0 + r1) * K + c1;
    const _Float16* b0 = Bt + (long)(n0 + r0) * K + c0;
    const _Float16* b1 = Bt + (long)(n0 + r1) * K + c1;

    const int fr = lane & 15;
    const int kb = (lane >> 4) << 3;  // k offset within BK=32: 0/8/16/24

    for (int k0 = 0; k0 < K; k0 += 32) {
        __syncthreads();
        ASYNC_COPY16(a0 + k0, As + e0);
        ASYNC_COPY16(a1 + k0, As + e1);
        ASYNC_COPY16(b0 + k0, Bs + e0);
        ASYNC_COPY16(b1 + k0, Bs + e1);
        __syncthreads();

        f16x8 af[4], bf[4];
#pragma unroll
        for (int i = 0; i < 4; i++)
            af[i] = *(const f16x8*)&As[(((wr << 6) + (i << 4) + fr) << 5) + kb];
#pragma unroll
        for (int j = 0; j < 4; j++)
            bf[j] = *(const f16x8*)&Bs[(((wc << 6) + (j << 4) + fr) << 5) + kb];
#pragma unroll
        for (int i = 0; i < 4; i++)
#pragma unroll
            for (int j = 0; j < 4; j++)
                acc[i][j] = __builtin_amdgcn_mfma_f32_16x16x32_f16(af[i], bf[j], acc[i][j], 0, 0, 0);
    }

    const int rsub = (lane >> 4) << 2;
    const float lsc = EPI ? ln_scale[0] : 0.f;
#pragma unroll
    for (int j = 0; j < 4; j++) {
        const int col = n0 + (wc << 6) + (j << 4) + fr;
        float ld = 0.f, lb = 0.f;
        if (EPI) { ld = ln_delta[col]; lb = ln_bias[col]; }
#pragma unroll
        for (int i = 0; i < 4; i++) {
            const int rbase = m0 + (wr << 6) + (i << 4) + rsub;
#pragma unroll
            for (int r = 0; r < 4; r++) {
                float v = acc[i][j][r];
                if (EPI) v = ld * tanhf(lsc * v) + lb;
                C[(long)(rbase + r) * N + col] = v;
            }
        }
    }
}

// ---------------- spiral: two steps on (q,k); v (3rd comp) NOT written back ----------------
__device__ __forceinline__ void spiral2(float& xi, float& xj, float xl)
{
    const float CS = 0.9950041652780258f;   // cos(0.1)
    const float SN = 0.09983341664682815f;  // sin(0.1)
#pragma unroll
    for (int s = 0; s < 2; s++) {
        float r = sqrtf(xi * xi + xj * xj + xl * xl);
        r = fmaxf(r, 1e-8f);
        const float coef = (6.0f - r) / r;   // radial = coef * x
        const float yi = CS * xi - SN * xj;
        const float yj = SN * xi + CS * xj;
        const float nxi = xi + 0.1f * (yi - xi + coef * xi);
        const float nxj = xj + 0.1f * (yj - xj + coef * xj);
        const float nxl = xl + 0.1f * (coef * xl);
        xi = nxi; xj = nxj; xl = nxl;
    }
}

// ---------------- local causal windowed attention, fused spiral, lane-per-row ----------------
// block = 128 threads handles 128 consecutive t of one (b,h).
// LDS tiles (f16, row stride 68 = pad): k'[144], v[144], q'[128] (q pre-scaled 1/8).
// Per lane: 17 banded dots over d=64 via v_dot2 (f32 accum), sink softmax, PV into 64 f32 regs.
#define TB   128
#define ROWS 144
#define LDR  68

__global__ __launch_bounds__(128) void attn_kernel(const float* __restrict__ qkv,
                                                   const float* __restrict__ sinks,
                                                   _Float16* __restrict__ yh)
{
    __shared__ __attribute__((aligned(16))) _Float16 k_lds[ROWS * LDR];
    __shared__ __attribute__((aligned(16))) _Float16 v_lds[ROWS * LDR];
    __shared__ __attribute__((aligned(16))) _Float16 q_lds[TB * LDR];

    const int tid = threadIdx.x;
    const int chunk = blockIdx.x & 15;
    const int h = (blockIdx.x >> 4) & 15;
    const int b = blockIdx.x >> 8;
    const int t0 = chunk * TB;
    const long bT = (long)b * T_DIM;

    // ---- staging: rows t0-16 .. t0+127, spiral^2 fused, f16 packs ----
    for (int s = tid; s < ROWS * 4; s += 128) {
        const int ri = s >> 2, q4 = s & 3;
        const int gr = min(max(t0 - 16 + ri, 0), T_DIM - 1);
        const float* base = qkv + (bT + gr) * 3072 + (h << 6) + (q4 << 4);
        float qq[16], kk[16], vv[16];
#pragma unroll
        for (int u = 0; u < 4; u++) {
            *(float4*)&qq[u * 4] = *(const float4*)(base + u * 4);
            *(float4*)&kk[u * 4] = *(const float4*)(base + 1024 + u * 4);
            *(float4*)&vv[u * 4] = *(const float4*)(base + 2048 + u * 4);
        }
#pragma unroll
        for (int u = 0; u < 16; u++) spiral2(qq[u], kk[u], vv[u]);  // vv unchanged (by value)
        const int lbase = ri * LDR + (q4 << 4);
#pragma unroll
        for (int u = 0; u < 8; u++) {
            f16x2 kp; kp[0] = (_Float16)kk[2 * u]; kp[1] = (_Float16)kk[2 * u + 1];
            *(f16x2*)&k_lds[lbase + 2 * u] = kp;
            f16x2 vp; vp[0] = (_Float16)vv[2 * u]; vp[1] = (_Float16)vv[2 * u + 1];
            *(f16x2*)&v_lds[lbase + 2 * u] = vp;
        }
        if (ri >= 16) {
            const int qbase = (ri - 16) * LDR + (q4 << 4);
#pragma unroll
            for (int u = 0; u < 8; u++) {
                f16x2 qp;
                qp[0] = (_Float16)(qq[2 * u] * 0.125f);
                qp[1] = (_Float16)(qq[2 * u + 1] * 0.125f);
                *(f16x2*)&q_lds[qbase + 2 * u] = qp;
            }
        }
    }
    __syncthreads();

    // ---- QK: 17 banded dots, lane-local over d ----
    float sc[17];
#pragma unroll
    for (int j = 0; j < 17; j++) sc[j] = 0.f;
    {
        const _Float16* qrow = &q_lds[tid * LDR];
        const _Float16* krow = &k_lds[tid * LDR];
        for (int dd = 0; dd < 32; ++dd) {
            f16x2 q2 = *(const f16x2*)(qrow + 2 * dd);
#pragma unroll
            for (int j = 0; j < 17; j++) {
                f16x2 k2 = *(const f16x2*)(krow + j * LDR + 2 * dd);
                sc[j] = FDOT2(q2, k2, sc[j]);
            }
        }
    }
    __syncthreads();  // q_lds reads done (reused as y staging below)

    // ---- mask + sink softmax (all in registers) ----
    const int t = t0 + tid;
#pragma unroll
    for (int j = 0; j < 17; j++)
        if (j + t < 16) sc[j] = -INFINITY;
    const float sink = sinks[h];
    float m = sink;
#pragma unroll
    for (int j = 0; j < 17; j++) m = fmaxf(m, sc[j]);
    float e[17];
    float denom = expf(sink - m);
#pragma unroll
    for (int j = 0; j < 17; j++) { e[j] = expf(sc[j] - m); denom += e[j]; }
    const float rden = 1.f / denom;
#pragma unroll
    for (int j = 0; j < 17; j++) e[j] *= rden;

    // ---- PV: 64 f32 accumulators, compile-time indexed ----
    float yacc[64];
#pragma unroll
    for (int d = 0; d < 64; d++) yacc[d] = 0.f;
    {
        const _Float16* vrow = &v_lds[tid * LDR];
        for (int j = 0; j < 17; j++) {
            const float a = e[j];
            const _Float16* vr = vrow + j * LDR;
#pragma unroll
            for (int dd = 0; dd < 32; dd++) {
                f16x2 v2 = *(const f16x2*)(vr + 2 * dd);
                yacc[2 * dd]     += a * (float)v2[0];
                yacc[2 * dd + 1] += a * (float)v2[1];
            }
        }
    }

    // ---- y -> LDS (reuse q_lds) -> coalesced f16 store ----
#pragma unroll
    for (int dd = 0; dd < 32; dd++) {
        f16x2 yp; yp[0] = (_Float16)yacc[2 * dd]; yp[1] = (_Float16)yacc[2 * dd + 1];
        *(f16x2*)&q_lds[tid * LDR + 2 * dd] = yp;
    }
    __syncthreads();
    const int w = tid & 31, rb = tid >> 5;
    _Float16* ybase = yh + (bT + t0) * 1024 + (h << 6);
#pragma unroll
    for (int it = 0; it < 32; it++) {
        const int r = (it << 2) + rb;
        *(unsigned int*)(ybase + (long)r * 1024 + (w << 1)) =
            *(const unsigned int*)&q_lds[r * LDR + (w << 1)];
    }
}

extern "C" void kernel_launch(void* const* d_in, const int* in_sizes, int n_in,
                              void* d_out, int out_size, void* d_ws, size_t ws_size,
                              hipStream_t stream)
{
    const float* x        = (const float*)d_in[0];
    const float* W_attn   = (const float*)d_in[1];
    const float* W_proj   = (const float*)d_in[2];
    const float* sinks    = (const float*)d_in[3];
    const float* ln_scale = (const float*)d_in[4];
    const float* ln_delta = (const float*)d_in[5];
    const float* ln_bias  = (const float*)d_in[6];
    float* out = (float*)d_out;

    char* ws = (char*)d_ws;
    _Float16* xh  = (_Float16*)(ws);                          //  8 MiB: 4096x1024 f16
    _Float16* WaT = (_Float16*)(ws + (size_t)( 8u << 20));    //  6 MiB: 3072x1024 f16
    _Float16* WpT = (_Float16*)(ws + (size_t)(14u << 20));    //  2 MiB: 1024x1024 f16
    float*    qkv = (float*)   (ws + (size_t)(16u << 20));    // 48 MiB: 4096x3072 f32
    _Float16* yh  = (_Float16*)(ws + (size_t)(64u << 20));    //  8 MiB: 4096x1024 f16

    // 1. x -> f16
    conv_x_kernel<<<4096, 256, 0, stream>>>(x, xh, 1048576);
    // 2. W_attn (1024x3072) -> WaT (3072x1024) f16
    transpose_f16_kernel<<<(1024 / 32) * (3072 / 32), 256, 0, stream>>>(W_attn, WaT, 1024, 3072);
    // 3. W_proj (1024x1024) -> WpT (1024x1024) f16
    transpose_f16_kernel<<<(1024 / 32) * (1024 / 32), 256, 0, stream>>>(W_proj, WpT, 1024, 1024);
    // 4. qkv = x @ W_attn   (M=4096, N=3072, K=1024)
    gemm_f16_kernel<0><<<32 * 24, 256, 0, stream>>>(xh, WaT, qkv, 4096, 3072, 1024,
                                                    nullptr, nullptr, nullptr);
    // 5+6. fused spiral^2 + local attention -> yh (f16, (b,t,h*64+d) layout)
    attn_kernel<<<512, 128, 0, stream>>>(qkv, sinks, yh);
    // 7. out = ln_delta * tanh(ln_scale * (yh @ W_proj)) + ln_bias
    gemm_f16_kernel<1><<<32 * 8, 256, 0, stream>>>(yh, WpT, out, 4096, 1024, 1024,
                                                   ln_scale, ln_delta, ln_bias);
}

// Round 4
// 182.642 us; speedup vs baseline: 1.7212x; 1.0859x over previous
//
#include <hip/hip_runtime.h>
#include <hip/hip_fp16.h>
#include <math.h>

#define T_DIM 2048
#define B_DIM 2
#define C_DIM 1024
#define H_DIM 16
#define M_DIM 4096   // B*T

typedef _Float16 f16x8 __attribute__((ext_vector_type(8)));
typedef _Float16 f16x4 __attribute__((ext_vector_type(4)));
typedef _Float16 f16x2 __attribute__((ext_vector_type(2)));
typedef float    f32x4 __attribute__((ext_vector_type(4)));

union f16x8_u { f16x8 v; f16x2 h[4]; _Float16 e[8]; };

#if defined(__has_builtin)
#  if __has_builtin(__builtin_amdgcn_fdot2)
#    define HAVE_FDOT2 1
#  endif
#endif

static __device__ __forceinline__ float FDOT2(f16x2 a, f16x2 b, float c)
{
#ifdef HAVE_FDOT2
    return __builtin_amdgcn_fdot2(a, b, c, false);
#else
    return c + (float)a[0] * (float)b[0] + (float)a[1] * (float)b[1];
#endif
}

// async global->LDS, 16 bytes per lane (wave-uniform base + lane*16 dest)
#define ASYNC_COPY16(gsrc, ldst) \
  __builtin_amdgcn_global_load_lds( \
    (__attribute__((address_space(1))) unsigned int*)(gsrc), \
    (__attribute__((address_space(3))) unsigned int*)(ldst), 16, 0, 0)

// ---------------- convert x (fp32) -> f16 ----------------
__global__ __launch_bounds__(256) void conv_x_kernel(const float* __restrict__ x,
                                                     _Float16* __restrict__ xh, int n4)
{
    int i = blockIdx.x * 256 + threadIdx.x;
    if (i >= n4) return;
    float4 v = ((const float4*)x)[i];
    f16x4 o;
    o[0] = (_Float16)v.x; o[1] = (_Float16)v.y;
    o[2] = (_Float16)v.z; o[3] = (_Float16)v.w;
    ((f16x4*)xh)[i] = o;
}

// ---------------- transpose + convert W (K x N fp32) -> WT (N x K f16) ----------------
__global__ __launch_bounds__(256) void transpose_f16_kernel(const float* __restrict__ W,
                                                            _Float16* __restrict__ WT,
                                                            int K, int N)
{
    __shared__ float tile[32][33];
    const int nbk = K >> 5;
    const int bk = blockIdx.x % nbk;
    const int bn = blockIdx.x / nbk;
    const int tx = threadIdx.x & 31, ty = threadIdx.x >> 5;
#pragma unroll
    for (int r = ty; r < 32; r += 8)
        tile[r][tx] = W[(long)(bk * 32 + r) * N + bn * 32 + tx];
    __syncthreads();
#pragma unroll
    for (int r = ty; r < 32; r += 8)
        WT[(long)(bn * 32 + r) * K + bk * 32 + tx] = (_Float16)tile[tx][r];
}

// ---------------- f16 MFMA GEMM: C[M,N] = A[M,K] * Bt[N,K]^T ----------------
// BM x 128 tile, BK=32, 4 waves, min-2-phase double-buffered pipeline (T3 recipe):
// STAGE(next) issued BEFORE ds_read+MFMA of current; one vmcnt(0)+barrier per K-step.
template<int BM, int EPI, int OUTF16>
__global__ __launch_bounds__(256) void gemm_f16_kernel(
    const _Float16* __restrict__ A, const _Float16* __restrict__ Bt,
    void* __restrict__ Cv, int M, int N, int K,
    const float* __restrict__ ln_scale, const float* __restrict__ ln_delta,
    const float* __restrict__ ln_bias)
{
    constexpr int M_REP   = BM / 32;   // 16-row fragments per wave along M
    constexpr int A_LOADS = BM / 64;   // 16B staging loads per thread for A
    __shared__ __attribute__((aligned(16))) _Float16 As[2][BM * 32];
    __shared__ __attribute__((aligned(16))) _Float16 Bs[2][128 * 32];

    const int tid  = threadIdx.x;
    const int lane = tid & 63;
    const int wave = tid >> 6;
    const int wr = wave >> 1, wc = wave & 1;
    const int ntn = N >> 7;
    const int m0 = (blockIdx.x / ntn) * BM;
    const int n0 = (blockIdx.x % ntn) << 7;

    f32x4 acc[M_REP][4] = {};

    const int ea = tid * 8;   // f16 elem offset of this thread's 16B staging chunk 0
    const _Float16* aptr[A_LOADS];
    const _Float16* bptr[2];
#pragma unroll
    for (int l = 0; l < A_LOADS; ++l) {
        const int e = ea + l * 2048;
        aptr[l] = A + (long)(m0 + (e >> 5)) * K + (e & 31);
    }
#pragma unroll
    for (int l = 0; l < 2; ++l) {
        const int e = ea + l * 2048;
        bptr[l] = Bt + (long)(n0 + (e >> 5)) * K + (e & 31);
    }

    const int fr = lane & 15;
    const int kb = (lane >> 4) << 3;  // k offset within BK=32
    const int NT = K >> 5;

    // prologue: stage tile 0 into buffer 0
#pragma unroll
    for (int l = 0; l < A_LOADS; ++l) ASYNC_COPY16(aptr[l], &As[0][ea + l * 2048]);
#pragma unroll
    for (int l = 0; l < 2; ++l)       ASYNC_COPY16(bptr[l], &Bs[0][ea + l * 2048]);
    asm volatile("s_waitcnt vmcnt(0)" ::: "memory");
    __syncthreads();

    int cur = 0;
    for (int t = 0; t < NT; ++t) {
        if (t + 1 < NT) {   // issue next-tile staging FIRST (in flight during compute)
            const int k0 = (t + 1) << 5;
#pragma unroll
            for (int l = 0; l < A_LOADS; ++l) ASYNC_COPY16(aptr[l] + k0, &As[cur ^ 1][ea + l * 2048]);
#pragma unroll
            for (int l = 0; l < 2; ++l)       ASYNC_COPY16(bptr[l] + k0, &Bs[cur ^ 1][ea + l * 2048]);
        }
        f16x8 af[M_REP], bf[4];
#pragma unroll
        for (int i = 0; i < M_REP; i++)
            af[i] = *(const f16x8*)&As[cur][((wr * (BM / 2) + (i << 4) + fr) << 5) + kb];
#pragma unroll
        for (int j = 0; j < 4; j++)
            bf[j] = *(const f16x8*)&Bs[cur][(((wc << 6) + (j << 4) + fr) << 5) + kb];
        __builtin_amdgcn_s_setprio(1);
#pragma unroll
        for (int i = 0; i < M_REP; i++)
#pragma unroll
            for (int j = 0; j < 4; j++)
                acc[i][j] = __builtin_amdgcn_mfma_f32_16x16x32_f16(af[i], bf[j], acc[i][j], 0, 0, 0);
        __builtin_amdgcn_s_setprio(0);
        if (t + 1 < NT) {
            asm volatile("s_waitcnt vmcnt(0)" ::: "memory");
            __syncthreads();
            cur ^= 1;
        }
    }

    // epilogue: C/D mapping col = lane&15, row = (lane>>4)*4 + r
    const int rsub = (lane >> 4) << 2;
    const float lsc = EPI ? ln_scale[0] : 0.f;
#pragma unroll
    for (int j = 0; j < 4; j++) {
        const int col = n0 + (wc << 6) + (j << 4) + fr;
        float ld = 0.f, lb = 0.f;
        if (EPI) { ld = ln_delta[col]; lb = ln_bias[col]; }
#pragma unroll
        for (int i = 0; i < M_REP; i++) {
            const int rbase = m0 + wr * (BM / 2) + (i << 4) + rsub;
#pragma unroll
            for (int r = 0; r < 4; r++) {
                float v = acc[i][j][r];
                if (EPI) v = ld * tanhf(lsc * v) + lb;
                if (OUTF16) ((_Float16*)Cv)[(long)(rbase + r) * N + col] = (_Float16)v;
                else        ((float*)Cv)[(long)(rbase + r) * N + col] = v;
            }
        }
    }
}

// ---------------- spiral: two steps on (q,k); v (3rd comp) by value ----------------
__device__ __forceinline__ void spiral2(float& xi, float& xj, float xl)
{
    const float CS = 0.9950041652780258f;   // cos(0.1)
    const float SN = 0.09983341664682815f;  // sin(0.1)
#pragma unroll
    for (int s = 0; s < 2; s++) {
        float r = sqrtf(xi * xi + xj * xj + xl * xl);
        r = fmaxf(r, 1e-8f);
        const float coef = (6.0f - r) / r;
        const float yi = CS * xi - SN * xj;
        const float yj = SN * xi + CS * xj;
        const float nxi = xi + 0.1f * (yi - xi + coef * xi);
        const float nxj = xj + 0.1f * (yj - xj + coef * xj);
        const float nxl = xl + 0.1f * (coef * xl);
        xi = nxi; xj = nxj; xl = nxl;
    }
}

// ---------------- local causal windowed attention, fused spiral, lane-per-row ----------------
// qkv is f16 now. LDR=72 (rows 144B, 16B-aligned): row-per-lane b128 reads are
// bank-uniform (bank base 4*lane mod 32 -> 8 accesses/bank = minimum).
#define TB   128
#define ROWS 144
#define LDR  72

__global__ __launch_bounds__(128) void attn_kernel(const _Float16* __restrict__ qkv,
                                                   const float* __restrict__ sinks,
                                                   _Float16* __restrict__ yh)
{
    __shared__ __attribute__((aligned(16))) _Float16 k_lds[ROWS * LDR];
    __shared__ __attribute__((aligned(16))) _Float16 v_lds[ROWS * LDR];
    __shared__ __attribute__((aligned(16))) _Float16 q_lds[TB * LDR];

    const int tid = threadIdx.x;
    const int chunk = blockIdx.x & 15;
    const int h = (blockIdx.x >> 4) & 15;
    const int b = blockIdx.x >> 8;
    const int t0 = chunk * TB;
    const long bT = (long)b * T_DIM;

    // ---- staging: rows t0-16 .. t0+127, spiral^2 fused ----
    for (int s = tid; s < ROWS * 4; s += 128) {
        const int ri = s >> 2, q4 = s & 3;
        const int gr = min(max(t0 - 16 + ri, 0), T_DIM - 1);
        const _Float16* base = qkv + (bT + gr) * 3072 + (h << 6) + (q4 << 4);
        f16x8_u qa, qb, ka, kb2, va, vb;
        qa.v  = *(const f16x8*)(base);        qb.v  = *(const f16x8*)(base + 8);
        ka.v  = *(const f16x8*)(base + 1024); kb2.v = *(const f16x8*)(base + 1032);
        va.v  = *(const f16x8*)(base + 2048); vb.v  = *(const f16x8*)(base + 2056);
        float qq[16], kk[16], vv[16];
#pragma unroll
        for (int u = 0; u < 8; u++) {
            qq[u] = (float)qa.e[u]; qq[8 + u] = (float)qb.e[u];
            kk[u] = (float)ka.e[u]; kk[8 + u] = (float)kb2.e[u];
            vv[u] = (float)va.e[u]; vv[8 + u] = (float)vb.e[u];
        }
#pragma unroll
        for (int u = 0; u < 16; u++) spiral2(qq[u], kk[u], vv[u]);  // vv by value
        const int lbase = ri * LDR + (q4 << 4);
        f16x8_u ko0, ko1, vo0, vo1;
#pragma unroll
        for (int u = 0; u < 8; u++) {
            ko0.e[u] = (_Float16)kk[u]; ko1.e[u] = (_Float16)kk[8 + u];
            vo0.e[u] = (_Float16)vv[u]; vo1.e[u] = (_Float16)vv[8 + u];
        }
        *(f16x8*)&k_lds[lbase]     = ko0.v;
        *(f16x8*)&k_lds[lbase + 8] = ko1.v;
        *(f16x8*)&v_lds[lbase]     = vo0.v;
        *(f16x8*)&v_lds[lbase + 8] = vo1.v;
        if (ri >= 16) {
            const int qbase = (ri - 16) * LDR + (q4 << 4);
            f16x8_u qo0, qo1;
#pragma unroll
            for (int u = 0; u < 8; u++) {
                qo0.e[u] = (_Float16)(qq[u] * 0.125f);
                qo1.e[u] = (_Float16)(qq[8 + u] * 0.125f);
            }
            *(f16x8*)&q_lds[qbase]     = qo0.v;
            *(f16x8*)&q_lds[qbase + 8] = qo1.v;
        }
    }
    __syncthreads();

    // ---- q row into registers (8 x b128) ----
    f16x8_u qv[8];
#pragma unroll
    for (int u = 0; u < 8; u++) qv[u].v = *(const f16x8*)&q_lds[tid * LDR + u * 8];

    // ---- QK: 17 banded dots, lane-local over d, b128 reads ----
    float sc[17];
#pragma unroll
    for (int j = 0; j < 17; j++) {
        const _Float16* kr = &k_lds[(tid + j) * LDR];
        float s = 0.f;
#pragma unroll
        for (int u = 0; u < 8; u++) {
            f16x8_u kx; kx.v = *(const f16x8*)&kr[u * 8];
#pragma unroll
            for (int p = 0; p < 4; p++) s = FDOT2(qv[u].h[p], kx.h[p], s);
        }
        sc[j] = s;
    }

    // ---- mask + sink softmax (registers) ----
    const int t = t0 + tid;
#pragma unroll
    for (int j = 0; j < 17; j++)
        if (j + t < 16) sc[j] = -INFINITY;
    const float sink = sinks[h];
    float m = sink;
#pragma unroll
    for (int j = 0; j < 17; j++) m = fmaxf(m, sc[j]);
    float e[17];
    float denom = expf(sink - m);
#pragma unroll
    for (int j = 0; j < 17; j++) { e[j] = expf(sc[j] - m); denom += e[j]; }
    const float rden = 1.f / denom;
#pragma unroll
    for (int j = 0; j < 17; j++) e[j] *= rden;

    // ---- PV: 64 f32 accumulators, b128 v reads ----
    float yacc[64];
#pragma unroll
    for (int d = 0; d < 64; d++) yacc[d] = 0.f;
#pragma unroll
    for (int j = 0; j < 17; j++) {
        const float a = e[j];
        const _Float16* vr = &v_lds[(tid + j) * LDR];
#pragma unroll
        for (int u = 0; u < 8; u++) {
            f16x8_u vx; vx.v = *(const f16x8*)&vr[u * 8];
#pragma unroll
            for (int z = 0; z < 8; z++) yacc[u * 8 + z] += a * (float)vx.e[z];
        }
    }

    // ---- y -> own q_lds row -> coalesced b128 store ----
#pragma unroll
    for (int u = 0; u < 8; u++) {
        f16x8_u yo;
#pragma unroll
        for (int z = 0; z < 8; z++) yo.e[z] = (_Float16)yacc[u * 8 + z];
        *(f16x8*)&q_lds[tid * LDR + u * 8] = yo.v;
    }
    __syncthreads();
    const int ch = tid & 7, rb = tid >> 3;
#pragma unroll
    for (int pass = 0; pass < 8; ++pass) {
        const int r = pass * 16 + rb;
        *(f16x8*)(yh + (bT + t0 + r) * 1024 + (h << 6) + ch * 8) =
            *(const f16x8*)&q_lds[r * LDR + ch * 8];
    }
}

extern "C" void kernel_launch(void* const* d_in, const int* in_sizes, int n_in,
                              void* d_out, int out_size, void* d_ws, size_t ws_size,
                              hipStream_t stream)
{
    const float* x        = (const float*)d_in[0];
    const float* W_attn   = (const float*)d_in[1];
    const float* W_proj   = (const float*)d_in[2];
    const float* sinks    = (const float*)d_in[3];
    const float* ln_scale = (const float*)d_in[4];
    const float* ln_delta = (const float*)d_in[5];
    const float* ln_bias  = (const float*)d_in[6];
    float* out = (float*)d_out;

    char* ws = (char*)d_ws;
    _Float16* xh    = (_Float16*)(ws);                          //  8 MiB: 4096x1024 f16
    _Float16* WaT   = (_Float16*)(ws + (size_t)( 8u << 20));    //  6 MiB: 3072x1024 f16
    _Float16* WpT   = (_Float16*)(ws + (size_t)(14u << 20));    //  2 MiB: 1024x1024 f16
    _Float16* qkv16 = (_Float16*)(ws + (size_t)(16u << 20));    // 24 MiB: 4096x3072 f16
    _Float16* yh    = (_Float16*)(ws + (size_t)(40u << 20));    //  8 MiB: 4096x1024 f16

    // 1. x -> f16
    conv_x_kernel<<<4096, 256, 0, stream>>>(x, xh, 1048576);
    // 2. W_attn (1024x3072) -> WaT (3072x1024) f16
    transpose_f16_kernel<<<(1024 / 32) * (3072 / 32), 256, 0, stream>>>(W_attn, WaT, 1024, 3072);
    // 3. W_proj (1024x1024) -> WpT (1024x1024) f16
    transpose_f16_kernel<<<(1024 / 32) * (1024 / 32), 256, 0, stream>>>(W_proj, WpT, 1024, 1024);
    // 4. qkv = x @ W_attn (f16 out)  M=4096, N=3072, K=1024
    gemm_f16_kernel<128, 0, 1><<<32 * 24, 256, 0, stream>>>(xh, WaT, qkv16, 4096, 3072, 1024,
                                                            nullptr, nullptr, nullptr);
    // 5+6. fused spiral^2 + local attention -> yh
    attn_kernel<<<512, 128, 0, stream>>>(qkv16, sinks, yh);
    // 7. out = ln_delta * tanh(ln_scale * (yh @ W_proj)) + ln_bias  (BM=64 -> 512 blocks, 2/CU)
    gemm_f16_kernel<64, 1, 0><<<64 * 8, 256, 0, stream>>>(yh, WpT, out, 4096, 1024, 1024,
                                                          ln_scale, ln_delta, ln_bias);
}

// Round 6
// 173.174 us; speedup vs baseline: 1.8153x; 1.0547x over previous
//
#include <hip/hip_runtime.h>
#include <hip/hip_fp16.h>
#include <math.h>

#define T_DIM 2048
#define B_DIM 2
#define C_DIM 1024
#define H_DIM 16
#define M_DIM 4096   // B*T

typedef _Float16 f16x8 __attribute__((ext_vector_type(8)));
typedef _Float16 f16x4 __attribute__((ext_vector_type(4)));
typedef _Float16 f16x2 __attribute__((ext_vector_type(2)));
typedef float    f32x4 __attribute__((ext_vector_type(4)));

union f16x8_u { f16x8 v; f16x2 h[4]; _Float16 e[8]; };

#if defined(__has_builtin)
#  if __has_builtin(__builtin_amdgcn_fdot2)
#    define HAVE_FDOT2 1
#  endif
#endif

static __device__ __forceinline__ float FDOT2(f16x2 a, f16x2 b, float c)
{
#ifdef HAVE_FDOT2
    return __builtin_amdgcn_fdot2(a, b, c, false);
#else
    return c + (float)a[0] * (float)b[0] + (float)a[1] * (float)b[1];
#endif
}

// async global->LDS, 16 bytes per lane (wave-uniform base + lane*16 dest)
#define ASYNC_COPY16(gsrc, ldst) \
  __builtin_amdgcn_global_load_lds( \
    (__attribute__((address_space(1))) unsigned int*)(gsrc), \
    (__attribute__((address_space(3))) unsigned int*)(ldst), 16, 0, 0)

// ---------------- fused prep: x->f16  +  both weight transposes ----------------
// grid: [0,4096) conv x; [4096,7168) transpose W_attn; [7168,8192) transpose W_proj
__global__ __launch_bounds__(256) void prep_kernel(const float* __restrict__ x,
                                                   const float* __restrict__ Wa,
                                                   const float* __restrict__ Wp,
                                                   _Float16* __restrict__ xh,
                                                   _Float16* __restrict__ WaT,
                                                   _Float16* __restrict__ WpT)
{
    __shared__ float tile[32][33];
    const int bid = blockIdx.x;
    const int tid = threadIdx.x;
    if (bid < 4096) {
        const int i = bid * 256 + tid;          // 1048576 float4 groups
        float4 v = ((const float4*)x)[i];
        f16x4 o;
        o[0] = (_Float16)v.x; o[1] = (_Float16)v.y;
        o[2] = (_Float16)v.z; o[3] = (_Float16)v.w;
        ((f16x4*)xh)[i] = o;
        return;
    }
    const float* W; _Float16* WT; int N, b;
    if (bid < 4096 + 3072) { W = Wa; WT = WaT; N = 3072; b = bid - 4096; }
    else                   { W = Wp; WT = WpT; N = 1024; b = bid - 7168; }
    const int K = 1024;
    const int bk = b & 31;        // 32 k-blocks
    const int bn = b >> 5;
    const int tx = tid & 31, ty = tid >> 5;
#pragma unroll
    for (int r = ty; r < 32; r += 8)
        tile[r][tx] = W[(long)(bk * 32 + r) * N + bn * 32 + tx];
    __syncthreads();
#pragma unroll
    for (int r = ty; r < 32; r += 8)
        WT[(long)(bn * 32 + r) * K + bk * 32 + tx] = (_Float16)tile[tx][r];
}

// ---------------- f16 MFMA GEMM: C[M,N] = A[M,K] * Bt[N,K]^T ----------------
// BM x 128 tile, BK=32, 4 waves. Ring-3 LDS slots + COUNTED vmcnt (T4):
// iteration t: issue stage(t+2) into slot freed at end of t-1, wait vmcnt(2*LPT)
// (tiles t+1,t+2 stay in flight ACROSS the barrier), barrier, compute, barrier.
template<int BM, int EPI, int OUTF16>
__global__ __launch_bounds__(256) void gemm_f16_kernel(
    const _Float16* __restrict__ A, const _Float16* __restrict__ Bt,
    void* __restrict__ Cv, int M, int N, int K,
    const float* __restrict__ ln_scale, const float* __restrict__ ln_delta,
    const float* __restrict__ ln_bias)
{
    constexpr int M_REP   = BM / 32;    // 16-row fragments per wave along M
    constexpr int A_LOADS = BM / 64;    // 16B staging loads per thread for A
    constexpr int LPT     = A_LOADS + 2;  // loads per thread per K-tile
    __shared__ __attribute__((aligned(16))) _Float16 As[3][BM * 32];
    __shared__ __attribute__((aligned(16))) _Float16 Bs[3][128 * 32];

    const int tid  = threadIdx.x;
    const int lane = tid & 63;
    const int wave = tid >> 6;
    const int wr = wave >> 1, wc = wave & 1;

    // XCD-aware bijective swizzle (gridDim.x % 8 == 0 for both gemms)
    const int nwg = gridDim.x;
    const int q8  = nwg >> 3;
    const int bid = ((int)blockIdx.x & 7) * q8 + ((int)blockIdx.x >> 3);

    const int ntn = N >> 7;
    const int m0 = (bid / ntn) * BM;
    const int n0 = (bid % ntn) << 7;

    f32x4 acc[M_REP][4] = {};

    const int ea = tid * 8;   // f16 elem offset of this thread's 16B staging chunk 0
    const _Float16* aptr[A_LOADS];
    const _Float16* bptr[2];
#pragma unroll
    for (int l = 0; l < A_LOADS; ++l) {
        const int e = ea + l * 2048;
        aptr[l] = A + (long)(m0 + (e >> 5)) * K + (e & 31);
    }
#pragma unroll
    for (int l = 0; l < 2; ++l) {
        const int e = ea + l * 2048;
        bptr[l] = Bt + (long)(n0 + (e >> 5)) * K + (e & 31);
    }

    const int fr = lane & 15;
    const int kb = (lane >> 4) << 3;  // k offset within BK=32
    const int NT = K >> 5;

    auto stage = [&](int tile, int slot) {
        const int k0 = tile << 5;
#pragma unroll
        for (int l = 0; l < A_LOADS; ++l) ASYNC_COPY16(aptr[l] + k0, &As[slot][ea + l * 2048]);
#pragma unroll
        for (int l = 0; l < 2; ++l)       ASYNC_COPY16(bptr[l] + k0, &Bs[slot][ea + l * 2048]);
    };

    // prologue: tiles 0,1 into slots 0,1
    stage(0, 0);
    stage(1, 1);

    int s = 0;  // slot holding tile t
    for (int t = 0; t < NT; ++t) {
        if (t + 2 < NT) {
            int s2 = s + 2; if (s2 >= 3) s2 -= 3;
            stage(t + 2, s2);   // slot freed by end-barrier of iteration t-1
        }
        const int rem = NT - 1 - t;
        if constexpr (LPT == 4) {
            if (rem >= 2)      asm volatile("s_waitcnt vmcnt(8)" ::: "memory");
            else if (rem == 1) asm volatile("s_waitcnt vmcnt(4)" ::: "memory");
            else               asm volatile("s_waitcnt vmcnt(0)" ::: "memory");
        } else {
            if (rem >= 2)      asm volatile("s_waitcnt vmcnt(6)" ::: "memory");
            else if (rem == 1) asm volatile("s_waitcnt vmcnt(3)" ::: "memory");
            else               asm volatile("s_waitcnt vmcnt(0)" ::: "memory");
        }
        __syncthreads();   // all waves' tile-t loads now landed

        f16x8 af[M_REP], bf[4];
#pragma unroll
        for (int i = 0; i < M_REP; i++)
            af[i] = *(const f16x8*)&As[s][((wr * (BM / 2) + (i << 4) + fr) << 5) + kb];
#pragma unroll
        for (int j = 0; j < 4; j++)
            bf[j] = *(const f16x8*)&Bs[s][(((wc << 6) + (j << 4) + fr) << 5) + kb];
        __builtin_amdgcn_s_setprio(1);
#pragma unroll
        for (int i = 0; i < M_REP; i++)
#pragma unroll
            for (int j = 0; j < 4; j++)
                acc[i][j] = __builtin_amdgcn_mfma_f32_16x16x32_f16(af[i], bf[j], acc[i][j], 0, 0, 0);
        __builtin_amdgcn_s_setprio(0);
        if (t + 1 < NT) __syncthreads();   // readers done -> slot s reusable
        ++s; if (s == 3) s = 0;
    }

    // epilogue: C/D mapping col = lane&15, row = (lane>>4)*4 + r
    const int rsub = (lane >> 4) << 2;
    const float lsc = EPI ? ln_scale[0] : 0.f;
#pragma unroll
    for (int j = 0; j < 4; j++) {
        const int col = n0 + (wc << 6) + (j << 4) + fr;
        float ld = 0.f, lb = 0.f;
        if (EPI) { ld = ln_delta[col]; lb = ln_bias[col]; }
#pragma unroll
        for (int i = 0; i < M_REP; i++) {
            const int rbase = m0 + wr * (BM / 2) + (i << 4) + rsub;
#pragma unroll
            for (int r = 0; r < 4; r++) {
                float v = acc[i][j][r];
                if (EPI) v = ld * tanhf(lsc * v) + lb;
                if (OUTF16) ((_Float16*)Cv)[(long)(rbase + r) * N + col] = (_Float16)v;
                else        ((float*)Cv)[(long)(rbase + r) * N + col] = v;
            }
        }
    }
}

// ---------------- spiral: two steps on (q,k); v (3rd comp) by value ----------------
__device__ __forceinline__ void spiral2(float& xi, float& xj, float xl)
{
    const float CS = 0.9950041652780258f;   // cos(0.1)
    const float SN = 0.09983341664682815f;  // sin(0.1)
#pragma unroll
    for (int s = 0; s < 2; s++) {
        float r = sqrtf(xi * xi + xj * xj + xl * xl);
        r = fmaxf(r, 1e-8f);
        const float coef = (6.0f - r) / r;
        const float yi = CS * xi - SN * xj;
        const float yj = SN * xi + CS * xj;
        const float nxi = xi + 0.1f * (yi - xi + coef * xi);
        const float nxj = xj + 0.1f * (yj - xj + coef * xj);
        const float nxl = xl + 0.1f * (coef * xl);
        xi = nxi; xj = nxj; xl = nxl;
    }
}

// ---------------- local causal windowed attention, fused spiral, lane-per-row ----------------
#define TB   128
#define ROWS 144
#define LDR  72

__global__ __launch_bounds__(128) void attn_kernel(const _Float16* __restrict__ qkv,
                                                   const float* __restrict__ sinks,
                                                   _Float16* __restrict__ yh)
{
    __shared__ __attribute__((aligned(16))) _Float16 k_lds[ROWS * LDR];
    __shared__ __attribute__((aligned(16))) _Float16 v_lds[ROWS * LDR];
    __shared__ __attribute__((aligned(16))) _Float16 q_lds[TB * LDR];

    const int tid = threadIdx.x;
    const int chunk = blockIdx.x & 15;
    const int h = (blockIdx.x >> 4) & 15;
    const int b = blockIdx.x >> 8;
    const int t0 = chunk * TB;
    const long bT = (long)b * T_DIM;

    // ---- staging: rows t0-16 .. t0+127, spiral^2 fused ----
    for (int s = tid; s < ROWS * 4; s += 128) {
        const int ri = s >> 2, q4 = s & 3;
        const int gr = min(max(t0 - 16 + ri, 0), T_DIM - 1);
        const _Float16* base = qkv + (bT + gr) * 3072 + (h << 6) + (q4 << 4);
        f16x8_u qa, qb, ka, kb2, va, vb;
        qa.v  = *(const f16x8*)(base);        qb.v  = *(const f16x8*)(base + 8);
        ka.v  = *(const f16x8*)(base + 1024); kb2.v = *(const f16x8*)(base + 1032);
        va.v  = *(const f16x8*)(base + 2048); vb.v  = *(const f16x8*)(base + 2056);
        float qq[16], kk[16], vv[16];
#pragma unroll
        for (int u = 0; u < 8; u++) {
            qq[u] = (float)qa.e[u]; qq[8 + u] = (float)qb.e[u];
            kk[u] = (float)ka.e[u]; kk[8 + u] = (float)kb2.e[u];
            vv[u] = (float)va.e[u]; vv[8 + u] = (float)vb.e[u];
        }
#pragma unroll
        for (int u = 0; u < 16; u++) spiral2(qq[u], kk[u], vv[u]);  // vv by value
        const int lbase = ri * LDR + (q4 << 4);
        f16x8_u ko0, ko1, vo0, vo1;
#pragma unroll
        for (int u = 0; u < 8; u++) {
            ko0.e[u] = (_Float16)kk[u]; ko1.e[u] = (_Float16)kk[8 + u];
            vo0.e[u] = (_Float16)vv[u]; vo1.e[u] = (_Float16)vv[8 + u];
        }
        *(f16x8*)&k_lds[lbase]     = ko0.v;
        *(f16x8*)&k_lds[lbase + 8] = ko1.v;
        *(f16x8*)&v_lds[lbase]     = vo0.v;
        *(f16x8*)&v_lds[lbase + 8] = vo1.v;
        if (ri >= 16) {
            const int qbase = (ri - 16) * LDR + (q4 << 4);
            f16x8_u qo0, qo1;
#pragma unroll
            for (int u = 0; u < 8; u++) {
                qo0.e[u] = (_Float16)(qq[u] * 0.125f);
                qo1.e[u] = (_Float16)(qq[8 + u] * 0.125f);
            }
            *(f16x8*)&q_lds[qbase]     = qo0.v;
            *(f16x8*)&q_lds[qbase + 8] = qo1.v;
        }
    }
    __syncthreads();

    // ---- q row into registers ----
    f16x8_u qv[8];
#pragma unroll
    for (int u = 0; u < 8; u++) qv[u].v = *(const f16x8*)&q_lds[tid * LDR + u * 8];

    // ---- QK: 17 banded dots, lane-local over d ----
    float sc[17];
#pragma unroll
    for (int j = 0; j < 17; j++) {
        const _Float16* kr = &k_lds[(tid + j) * LDR];
        float s = 0.f;
#pragma unroll
        for (int u = 0; u < 8; u++) {
            f16x8_u kx; kx.v = *(const f16x8*)&kr[u * 8];
#pragma unroll
            for (int p = 0; p < 4; p++) s = FDOT2(qv[u].h[p], kx.h[p], s);
        }
        sc[j] = s;
    }

    // ---- mask + sink softmax (registers) ----
    const int t = t0 + tid;
#pragma unroll
    for (int j = 0; j < 17; j++)
        if (j + t < 16) sc[j] = -INFINITY;
    const float sink = sinks[h];
    float m = sink;
#pragma unroll
    for (int j = 0; j < 17; j++) m = fmaxf(m, sc[j]);
    float e[17];
    float denom = expf(sink - m);
#pragma unroll
    for (int j = 0; j < 17; j++) { e[j] = expf(sc[j] - m); denom += e[j]; }
    const float rden = 1.f / denom;
#pragma unroll
    for (int j = 0; j < 17; j++) e[j] *= rden;

    // ---- PV: 64 f32 accumulators ----
    float yacc[64];
#pragma unroll
    for (int d = 0; d < 64; d++) yacc[d] = 0.f;
#pragma unroll
    for (int j = 0; j < 17; j++) {
        const float a = e[j];
        const _Float16* vr = &v_lds[(tid + j) * LDR];
#pragma unroll
        for (int u = 0; u < 8; u++) {
            f16x8_u vx; vx.v = *(const f16x8*)&vr[u * 8];
#pragma unroll
            for (int z = 0; z < 8; z++) yacc[u * 8 + z] += a * (float)vx.e[z];
        }
    }

    // ---- y -> own q_lds row -> coalesced b128 store ----
#pragma unroll
    for (int u = 0; u < 8; u++) {
        f16x8_u yo;
#pragma unroll
        for (int z = 0; z < 8; z++) yo.e[z] = (_Float16)yacc[u * 8 + z];
        *(f16x8*)&q_lds[tid * LDR + u * 8] = yo.v;
    }
    __syncthreads();
    const int ch = tid & 7, rb = tid >> 3;
#pragma unroll
    for (int pass = 0; pass < 8; ++pass) {
        const int r = pass * 16 + rb;
        *(f16x8*)(yh + (bT + t0 + r) * 1024 + (h << 6) + ch * 8) =
            *(const f16x8*)&q_lds[r * LDR + ch * 8];
    }
}

extern "C" void kernel_launch(void* const* d_in, const int* in_sizes, int n_in,
                              void* d_out, int out_size, void* d_ws, size_t ws_size,
                              hipStream_t stream)
{
    const float* x        = (const float*)d_in[0];
    const float* W_attn   = (const float*)d_in[1];
    const float* W_proj   = (const float*)d_in[2];
    const float* sinks    = (const float*)d_in[3];
    const float* ln_scale = (const float*)d_in[4];
    const float* ln_delta = (const float*)d_in[5];
    const float* ln_bias  = (const float*)d_in[6];
    float* out = (float*)d_out;

    char* ws = (char*)d_ws;
    _Float16* xh    = (_Float16*)(ws);                          //  8 MiB: 4096x1024 f16
    _Float16* WaT   = (_Float16*)(ws + (size_t)( 8u << 20));    //  6 MiB: 3072x1024 f16
    _Float16* WpT   = (_Float16*)(ws + (size_t)(14u << 20));    //  2 MiB: 1024x1024 f16
    _Float16* qkv16 = (_Float16*)(ws + (size_t)(16u << 20));    // 24 MiB: 4096x3072 f16
    _Float16* yh    = (_Float16*)(ws + (size_t)(40u << 20));    //  8 MiB: 4096x1024 f16

    // 1. fused prep: x->f16 + transpose/convert both weight matrices
    prep_kernel<<<8192, 256, 0, stream>>>(x, W_attn, W_proj, xh, WaT, WpT);
    // 2. qkv = x @ W_attn (f16 out)  M=4096, N=3072, K=1024   (768 blocks, 3/CU)
    gemm_f16_kernel<128, 0, 1><<<32 * 24, 256, 0, stream>>>(xh, WaT, qkv16, 4096, 3072, 1024,
                                                            nullptr, nullptr, nullptr);
    // 3. fused spiral^2 + local attention -> yh
    attn_kernel<<<512, 128, 0, stream>>>(qkv16, sinks, yh);
    // 4. out = ln_delta * tanh(ln_scale * (yh @ W_proj)) + ln_bias  (512 blocks, 2/CU)
    gemm_f16_kernel<64, 1, 0><<<64 * 8, 256, 0, stream>>>(yh, WpT, out, 4096, 1024, 1024,
                                                          ln_scale, ln_delta, ln_bias);
}

// Round 7
// 172.640 us; speedup vs baseline: 1.8209x; 1.0031x over previous
//
#include <hip/hip_runtime.h>
#include <hip/hip_fp16.h>
#include <math.h>

#define T_DIM 2048
#define B_DIM 2
#define C_DIM 1024
#define H_DIM 16
#define M_DIM 4096   // B*T

typedef _Float16 f16x8 __attribute__((ext_vector_type(8)));
typedef _Float16 f16x4 __attribute__((ext_vector_type(4)));
typedef _Float16 f16x2 __attribute__((ext_vector_type(2)));
typedef float    f32x4 __attribute__((ext_vector_type(4)));

union f16x8_u { f16x8 v; f16x2 h[4]; _Float16 e[8]; };

#if defined(__has_builtin)
#  if __has_builtin(__builtin_amdgcn_fdot2)
#    define HAVE_FDOT2 1
#  endif
#endif

static __device__ __forceinline__ float FDOT2(f16x2 a, f16x2 b, float c)
{
#ifdef HAVE_FDOT2
    return __builtin_amdgcn_fdot2(a, b, c, false);
#else
    return c + (float)a[0] * (float)b[0] + (float)a[1] * (float)b[1];
#endif
}

// async global->LDS, 16 bytes per lane (wave-uniform base + lane*16 dest)
#define ASYNC_COPY16(gsrc, ldst) \
  __builtin_amdgcn_global_load_lds( \
    (__attribute__((address_space(1))) unsigned int*)(gsrc), \
    (__attribute__((address_space(3))) unsigned int*)(ldst), 16, 0, 0)

// ---------------- fused prep: x->f16  +  both weight transposes ----------------
// grid: [0,4096) conv x; [4096,7168) transpose W_attn; [7168,8192) transpose W_proj
__global__ __launch_bounds__(256) void prep_kernel(const float* __restrict__ x,
                                                   const float* __restrict__ Wa,
                                                   const float* __restrict__ Wp,
                                                   _Float16* __restrict__ xh,
                                                   _Float16* __restrict__ WaT,
                                                   _Float16* __restrict__ WpT)
{
    __shared__ float tile[32][33];
    const int bid = blockIdx.x;
    const int tid = threadIdx.x;
    if (bid < 4096) {
        const int i = bid * 256 + tid;          // 1048576 float4 groups
        float4 v = ((const float4*)x)[i];
        f16x4 o;
        o[0] = (_Float16)v.x; o[1] = (_Float16)v.y;
        o[2] = (_Float16)v.z; o[3] = (_Float16)v.w;
        ((f16x4*)xh)[i] = o;
        return;
    }
    const float* W; _Float16* WT; int N, b;
    if (bid < 4096 + 3072) { W = Wa; WT = WaT; N = 3072; b = bid - 4096; }
    else                   { W = Wp; WT = WpT; N = 1024; b = bid - 7168; }
    const int K = 1024;
    const int bk = b & 31;        // 32 k-blocks
    const int bn = b >> 5;
    const int tx = tid & 31, ty = tid >> 5;
#pragma unroll
    for (int r = ty; r < 32; r += 8)
        tile[r][tx] = W[(long)(bk * 32 + r) * N + bn * 32 + tx];
    __syncthreads();
#pragma unroll
    for (int r = ty; r < 32; r += 8)
        WT[(long)(bn * 32 + r) * K + bk * 32 + tx] = (_Float16)tile[tx][r];
}

// ---------------- f16 MFMA GEMM: C[M,N] = A[M,K] * Bt[N,K]^T ----------------
// BM x 128 tile, BK=32, 4 waves. Ring-3 LDS slots + COUNTED vmcnt (T4) +
// bank-conflict element swizzle (T2): within each [row][32] f16 tile,
//   e_phys = e_log ^ (((row&2)<<3) | ((row&4)<<1))   (involution, 16B/32B chunks)
// Applied on BOTH sides (rule #21): global SOURCE col pre-permuted per staging
// lane (LDS dest stays linear for global_load_lds); ds_read applies same XOR.
// Post-swizzle: 16-lane fragment reads spread over all 32 banks at 2-way (free).
template<int BM, int EPI, int OUTF16>
__global__ __launch_bounds__(256) void gemm_f16_kernel(
    const _Float16* __restrict__ A, const _Float16* __restrict__ Bt,
    void* __restrict__ Cv, int M, int N, int K,
    const float* __restrict__ ln_scale, const float* __restrict__ ln_delta,
    const float* __restrict__ ln_bias)
{
    constexpr int M_REP   = BM / 32;    // 16-row fragments per wave along M
    constexpr int A_LOADS = BM / 64;    // 16B staging loads per thread for A
    constexpr int LPT     = A_LOADS + 2;  // loads per thread per K-tile
    __shared__ __attribute__((aligned(16))) _Float16 As[3][BM * 32];
    __shared__ __attribute__((aligned(16))) _Float16 Bs[3][128 * 32];

    const int tid  = threadIdx.x;
    const int lane = tid & 63;
    const int wave = tid >> 6;
    const int wr = wave >> 1, wc = wave & 1;

    // XCD-aware bijective swizzle (gridDim.x % 8 == 0 for both gemms)
    const int nwg = gridDim.x;
    const int q8  = nwg >> 3;
    const int bid = ((int)blockIdx.x & 7) * q8 + ((int)blockIdx.x >> 3);

    const int ntn = N >> 7;
    const int m0 = (bid / ntn) * BM;
    const int n0 = (bid % ntn) << 7;

    f32x4 acc[M_REP][4] = {};

    // staging: thread's linear 16B chunk p: row = p>>5 (+64 per extra load,
    // row bits 1,2 invariant), col = p&31. Source col gets the inverse swizzle.
    const int ea   = tid * 8;
    const int erow = ea >> 5;
    const int xm   = ((erow & 2) << 3) | ((erow & 4) << 1);
    const int ecs  = (ea & 31) ^ xm;    // pre-swizzled source col (f16 units)
    const _Float16* aptr[A_LOADS];
    const _Float16* bptr[2];
#pragma unroll
    for (int l = 0; l < A_LOADS; ++l)
        aptr[l] = A + (long)(m0 + erow + l * 64) * K + ecs;
#pragma unroll
    for (int l = 0; l < 2; ++l)
        bptr[l] = Bt + (long)(n0 + erow + l * 64) * K + ecs;

    const int fr = lane & 15;
    const int kb = (lane >> 4) << 3;                    // logical k offset
    const int xr = ((fr & 2) << 3) | ((fr & 4) << 1);   // read-side swizzle
    const int kbs = kb ^ xr;                            // physical k offset
    const int NT = K >> 5;

    auto stage = [&](int tile, int slot) {
        const int k0 = tile << 5;
#pragma unroll
        for (int l = 0; l < A_LOADS; ++l) ASYNC_COPY16(aptr[l] + k0, &As[slot][ea + l * 2048]);
#pragma unroll
        for (int l = 0; l < 2; ++l)       ASYNC_COPY16(bptr[l] + k0, &Bs[slot][ea + l * 2048]);
    };

    // prologue: tiles 0,1 into slots 0,1
    stage(0, 0);
    stage(1, 1);

    int s = 0;  // slot holding tile t
    for (int t = 0; t < NT; ++t) {
        if (t + 2 < NT) {
            int s2 = s + 2; if (s2 >= 3) s2 -= 3;
            stage(t + 2, s2);   // slot freed by end-barrier of iteration t-1
        }
        const int rem = NT - 1 - t;
        if constexpr (LPT == 4) {
            if (rem >= 2)      asm volatile("s_waitcnt vmcnt(8)" ::: "memory");
            else if (rem == 1) asm volatile("s_waitcnt vmcnt(4)" ::: "memory");
            else               asm volatile("s_waitcnt vmcnt(0)" ::: "memory");
        } else {
            if (rem >= 2)      asm volatile("s_waitcnt vmcnt(6)" ::: "memory");
            else if (rem == 1) asm volatile("s_waitcnt vmcnt(3)" ::: "memory");
            else               asm volatile("s_waitcnt vmcnt(0)" ::: "memory");
        }
        __syncthreads();   // all waves' tile-t loads now landed

        f16x8 af[M_REP], bf[4];
#pragma unroll
        for (int i = 0; i < M_REP; i++)
            af[i] = *(const f16x8*)&As[s][((wr * (BM / 2) + (i << 4) + fr) << 5) + kbs];
#pragma unroll
        for (int j = 0; j < 4; j++)
            bf[j] = *(const f16x8*)&Bs[s][(((wc << 6) + (j << 4) + fr) << 5) + kbs];
        __builtin_amdgcn_s_setprio(1);
#pragma unroll
        for (int i = 0; i < M_REP; i++)
#pragma unroll
            for (int j = 0; j < 4; j++)
                acc[i][j] = __builtin_amdgcn_mfma_f32_16x16x32_f16(af[i], bf[j], acc[i][j], 0, 0, 0);
        __builtin_amdgcn_s_setprio(0);
        if (t + 1 < NT) __syncthreads();   // readers done -> slot s reusable
        ++s; if (s == 3) s = 0;
    }

    // epilogue: C/D mapping col = lane&15, row = (lane>>4)*4 + r
    const int rsub = (lane >> 4) << 2;
    const float lsc = EPI ? ln_scale[0] : 0.f;
#pragma unroll
    for (int j = 0; j < 4; j++) {
        const int col = n0 + (wc << 6) + (j << 4) + fr;
        float ld = 0.f, lb = 0.f;
        if (EPI) { ld = ln_delta[col]; lb = ln_bias[col]; }
#pragma unroll
        for (int i = 0; i < M_REP; i++) {
            const int rbase = m0 + wr * (BM / 2) + (i << 4) + rsub;
#pragma unroll
            for (int r = 0; r < 4; r++) {
                float v = acc[i][j][r];
                if (EPI) v = ld * tanhf(lsc * v) + lb;
                if (OUTF16) ((_Float16*)Cv)[(long)(rbase + r) * N + col] = (_Float16)v;
                else        ((float*)Cv)[(long)(rbase + r) * N + col] = v;
            }
        }
    }
}

// ---------------- spiral: two steps on (q,k); v (3rd comp) by value ----------------
__device__ __forceinline__ void spiral2(float& xi, float& xj, float xl)
{
    const float CS = 0.9950041652780258f;   // cos(0.1)
    const float SN = 0.09983341664682815f;  // sin(0.1)
#pragma unroll
    for (int s = 0; s < 2; s++) {
        float r = sqrtf(xi * xi + xj * xj + xl * xl);
        r = fmaxf(r, 1e-8f);
        const float coef = (6.0f - r) / r;
        const float yi = CS * xi - SN * xj;
        const float yj = SN * xi + CS * xj;
        const float nxi = xi + 0.1f * (yi - xi + coef * xi);
        const float nxj = xj + 0.1f * (yj - xj + coef * xj);
        const float nxl = xl + 0.1f * (coef * xl);
        xi = nxi; xj = nxj; xl = nxl;
    }
}

// ---------------- local causal windowed attention, fused spiral, lane-per-row ----------------
#define TB   128
#define ROWS 144
#define LDR  72

__global__ __launch_bounds__(128) void attn_kernel(const _Float16* __restrict__ qkv,
                                                   const float* __restrict__ sinks,
                                                   _Float16* __restrict__ yh)
{
    __shared__ __attribute__((aligned(16))) _Float16 k_lds[ROWS * LDR];
    __shared__ __attribute__((aligned(16))) _Float16 v_lds[ROWS * LDR];
    __shared__ __attribute__((aligned(16))) _Float16 q_lds[TB * LDR];

    const int tid = threadIdx.x;
    const int chunk = blockIdx.x & 15;
    const int h = (blockIdx.x >> 4) & 15;
    const int b = blockIdx.x >> 8;
    const int t0 = chunk * TB;
    const long bT = (long)b * T_DIM;

    // ---- staging: rows t0-16 .. t0+127, spiral^2 fused ----
    for (int s = tid; s < ROWS * 4; s += 128) {
        const int ri = s >> 2, q4 = s & 3;
        const int gr = min(max(t0 - 16 + ri, 0), T_DIM - 1);
        const _Float16* base = qkv + (bT + gr) * 3072 + (h << 6) + (q4 << 4);
        f16x8_u qa, qb, ka, kb2, va, vb;
        qa.v  = *(const f16x8*)(base);        qb.v  = *(const f16x8*)(base + 8);
        ka.v  = *(const f16x8*)(base + 1024); kb2.v = *(const f16x8*)(base + 1032);
        va.v  = *(const f16x8*)(base + 2048); vb.v  = *(const f16x8*)(base + 2056);
        float qq[16], kk[16], vv[16];
#pragma unroll
        for (int u = 0; u < 8; u++) {
            qq[u] = (float)qa.e[u]; qq[8 + u] = (float)qb.e[u];
            kk[u] = (float)ka.e[u]; kk[8 + u] = (float)kb2.e[u];
            vv[u] = (float)va.e[u]; vv[8 + u] = (float)vb.e[u];
        }
#pragma unroll
        for (int u = 0; u < 16; u++) spiral2(qq[u], kk[u], vv[u]);  // vv by value
        const int lbase = ri * LDR + (q4 << 4);
        f16x8_u ko0, ko1, vo0, vo1;
#pragma unroll
        for (int u = 0; u < 8; u++) {
            ko0.e[u] = (_Float16)kk[u]; ko1.e[u] = (_Float16)kk[8 + u];
            vo0.e[u] = (_Float16)vv[u]; vo1.e[u] = (_Float16)vv[8 + u];
        }
        *(f16x8*)&k_lds[lbase]     = ko0.v;
        *(f16x8*)&k_lds[lbase + 8] = ko1.v;
        *(f16x8*)&v_lds[lbase]     = vo0.v;
        *(f16x8*)&v_lds[lbase + 8] = vo1.v;
        if (ri >= 16) {
            const int qbase = (ri - 16) * LDR + (q4 << 4);
            f16x8_u qo0, qo1;
#pragma unroll
            for (int u = 0; u < 8; u++) {
                qo0.e[u] = (_Float16)(qq[u] * 0.125f);
                qo1.e[u] = (_Float16)(qq[8 + u] * 0.125f);
            }
            *(f16x8*)&q_lds[qbase]     = qo0.v;
            *(f16x8*)&q_lds[qbase + 8] = qo1.v;
        }
    }
    __syncthreads();

    // ---- q row into registers ----
    f16x8_u qv[8];
#pragma unroll
    for (int u = 0; u < 8; u++) qv[u].v = *(const f16x8*)&q_lds[tid * LDR + u * 8];

    // ---- QK: 17 banded dots, lane-local over d ----
    float sc[17];
#pragma unroll
    for (int j = 0; j < 17; j++) {
        const _Float16* kr = &k_lds[(tid + j) * LDR];
        float s = 0.f;
#pragma unroll
        for (int u = 0; u < 8; u++) {
            f16x8_u kx; kx.v = *(const f16x8*)&kr[u * 8];
#pragma unroll
            for (int p = 0; p < 4; p++) s = FDOT2(qv[u].h[p], kx.h[p], s);
        }
        sc[j] = s;
    }

    // ---- mask + sink softmax (registers) ----
    const int t = t0 + tid;
#pragma unroll
    for (int j = 0; j < 17; j++)
        if (j + t < 16) sc[j] = -INFINITY;
    const float sink = sinks[h];
    float m = sink;
#pragma unroll
    for (int j = 0; j < 17; j++) m = fmaxf(m, sc[j]);
    float e[17];
    float denom = expf(sink - m);
#pragma unroll
    for (int j = 0; j < 17; j++) { e[j] = expf(sc[j] - m); denom += e[j]; }
    const float rden = 1.f / denom;
#pragma unroll
    for (int j = 0; j < 17; j++) e[j] *= rden;

    // ---- PV: 64 f32 accumulators ----
    float yacc[64];
#pragma unroll
    for (int d = 0; d < 64; d++) yacc[d] = 0.f;
#pragma unroll
    for (int j = 0; j < 17; j++) {
        const float a = e[j];
        const _Float16* vr = &v_lds[(tid + j) * LDR];
#pragma unroll
        for (int u = 0; u < 8; u++) {
            f16x8_u vx; vx.v = *(const f16x8*)&vr[u * 8];
#pragma unroll
            for (int z = 0; z < 8; z++) yacc[u * 8 + z] += a * (float)vx.e[z];
        }
    }

    // ---- y -> own q_lds row -> coalesced b128 store ----
#pragma unroll
    for (int u = 0; u < 8; u++) {
        f16x8_u yo;
#pragma unroll
        for (int z = 0; z < 8; z++) yo.e[z] = (_Float16)yacc[u * 8 + z];
        *(f16x8*)&q_lds[tid * LDR + u * 8] = yo.v;
    }
    __syncthreads();
    const int ch = tid & 7, rb = tid >> 3;
#pragma unroll
    for (int pass = 0; pass < 8; ++pass) {
        const int r = pass * 16 + rb;
        *(f16x8*)(yh + (bT + t0 + r) * 1024 + (h << 6) + ch * 8) =
            *(const f16x8*)&q_lds[r * LDR + ch * 8];
    }
}

extern "C" void kernel_launch(void* const* d_in, const int* in_sizes, int n_in,
                              void* d_out, int out_size, void* d_ws, size_t ws_size,
                              hipStream_t stream)
{
    const float* x        = (const float*)d_in[0];
    const float* W_attn   = (const float*)d_in[1];
    const float* W_proj   = (const float*)d_in[2];
    const float* sinks    = (const float*)d_in[3];
    const float* ln_scale = (const float*)d_in[4];
    const float* ln_delta = (const float*)d_in[5];
    const float* ln_bias  = (const float*)d_in[6];
    float* out = (float*)d_out;

    char* ws = (char*)d_ws;
    _Float16* xh    = (_Float16*)(ws);                          //  8 MiB: 4096x1024 f16
    _Float16* WaT   = (_Float16*)(ws + (size_t)( 8u << 20));    //  6 MiB: 3072x1024 f16
    _Float16* WpT   = (_Float16*)(ws + (size_t)(14u << 20));    //  2 MiB: 1024x1024 f16
    _Float16* qkv16 = (_Float16*)(ws + (size_t)(16u << 20));    // 24 MiB: 4096x3072 f16
    _Float16* yh    = (_Float16*)(ws + (size_t)(40u << 20));    //  8 MiB: 4096x1024 f16

    // 1. fused prep: x->f16 + transpose/convert both weight matrices
    prep_kernel<<<8192, 256, 0, stream>>>(x, W_attn, W_proj, xh, WaT, WpT);
    // 2. qkv = x @ W_attn (f16 out)  M=4096, N=3072, K=1024   (768 blocks, 3/CU)
    gemm_f16_kernel<128, 0, 1><<<32 * 24, 256, 0, stream>>>(xh, WaT, qkv16, 4096, 3072, 1024,
                                                            nullptr, nullptr, nullptr);
    // 3. fused spiral^2 + local attention -> yh
    attn_kernel<<<512, 128, 0, stream>>>(qkv16, sinks, yh);
    // 4. out = ln_delta * tanh(ln_scale * (yh @ W_proj)) + ln_bias  (512 blocks, 2/CU)
    gemm_f16_kernel<64, 1, 0><<<64 * 8, 256, 0, stream>>>(yh, WpT, out, 4096, 1024, 1024,
                                                          ln_scale, ln_delta, ln_bias);
}